// Round 8
// baseline (160.183 us; speedup 1.0000x reference)
//
#include <hip/hip_runtime.h>
#include <hip/hip_bf16.h>

// CrossModalContrastiveLoss: B=8, C=256, H=W=32 -> N=8192 vectors of dim 256.
// loss = -( P - 1024 * sum_i log(sum_j exp(S_ij)) ) / 8388608,
// S = normalize(rgb) @ normalize(x)^T / 0.1.
// P analytic from per-batch sums (round 7, verified): positives for row i are
// cols j with j%8 == i/1024 -> P = 10 * sum_b rgbsum_b . xsum_b.
//
// Round-8 gemm: BARRIER-FREE main loop. Block = 4 waves, 128 rows x 1024-col
// strip. A (128x256) staged once to LDS (proven XOR swizzle, conflict-free),
// ONE __syncthreads, then each wave independently streams 8 chunks of 64
// cols: B-fragments loaded DIRECT from global (same coalesced 16-line
// pattern as A-reg loads; strip is XCD-pinned so B sits in that XCD's L2),
// A-fragments via ds_read_b128, 128 MFMA + 64 exp2 per chunk. No per-chunk
// barriers -> wave stalls are hidden by the 7 other resident waves/CU.
// 2 blocks/CU (64 KB LDS each, 256-reg budget).

#define HWsz 1024
#define Cdim 256
#define Nvec 8192
#define CHW  (Cdim * HWsz)
#define NBLK 512   // 8 strips x 64 rowgroups

typedef __attribute__((ext_vector_type(8))) short bf16x8;
typedef __attribute__((ext_vector_type(4))) float f32x4;

__device__ inline unsigned short f2bf(float f) {
  unsigned int u = __float_as_uint(f);
  u += 0x7FFFu + ((u >> 16) & 1u);   // round-to-nearest-even
  return (unsigned short)(u >> 16);
}

// 32 vectors per block (all one batch), C split 8 ways. Also accumulates the
// per-batch channel sums of the normalized bf16 vectors (for analytic P).
__global__ __launch_bounds__(256) void norm_kernel(
    const float* __restrict__ rgb, const float* __restrict__ x,
    unsigned short* __restrict__ rgbn, unsigned short* __restrict__ xn,
    float* __restrict__ bsums) {
  __shared__ float ssp[8][32];
  __shared__ unsigned short tile[32][264];  // +8 pad
  const int t = threadIdx.x;
  const int nl = t & 31;        // vector within block
  const int part = t >> 5;      // 0..7: channel chunk
  const float* src = (blockIdx.y == 0) ? rgb : x;
  unsigned short* dst = (blockIdx.y == 0) ? rgbn : xn;
  const int n0 = blockIdx.x * 32;
  const int n = n0 + nl;
  const int b = n >> 10;        // uniform per block (32 | 1024)
  const int hw = n & 1023;
  const float* p = src + (size_t)b * CHW + (size_t)(part * 32) * HWsz + hw;

  float v[32];
  float ss = 0.f;
#pragma unroll
  for (int j = 0; j < 32; ++j) {
    v[j] = p[(size_t)j * HWsz];
    ss += v[j] * v[j];
  }
  ssp[part][nl] = ss;
  __syncthreads();
  float tot = 0.f;
#pragma unroll
  for (int q = 0; q < 8; ++q) tot += ssp[q][nl];
  const float inv = 1.0f / fmaxf(sqrtf(tot), 1e-12f);

#pragma unroll
  for (int c0 = 0; c0 < 32; c0 += 8) {
    unsigned short tmp[8];
#pragma unroll
    for (int j = 0; j < 8; ++j) tmp[j] = f2bf(v[c0 + j] * inv);
    *reinterpret_cast<uint4*>(&tile[nl][part * 32 + c0]) =
        *reinterpret_cast<const uint4*>(tmp);
  }
  __syncthreads();

#pragma unroll
  for (int pass = 0; pass < 4; ++pass) {
    const int r = pass * 8 + (t >> 5);
    const int ck = (t & 31) * 8;
    *reinterpret_cast<uint4*>(dst + (size_t)(n0 + r) * Cdim + ck) =
        *reinterpret_cast<const uint4*>(&tile[r][ck]);
  }

  // per-channel column sum over this block's 32 vectors -> batch sums
  float csum = 0.f;
#pragma unroll
  for (int r = 0; r < 32; ++r)
    csum += __uint_as_float((unsigned int)tile[r][t] << 16);
  atomicAdd(&bsums[(blockIdx.y ? 2048 : 0) + b * 256 + t], csum);
}

__global__ __launch_bounds__(256, 2) void gemm_loss_kernel(
    const unsigned short* __restrict__ A, const unsigned short* __restrict__ Bm,
    float* __restrict__ sumexp, const float* __restrict__ bsums,
    unsigned int* __restrict__ done, float* __restrict__ out) {
  // A tile 128 rows x 256 k, swizzled: sA[(kc*128+row)*64 + (cg^(row&7))*8]
  // (cg = 16-B unit within the 64-k block kc). 64 KB.
  __shared__ unsigned short sA[128 * 256];
  __shared__ float part4[4], part4b[4];
  __shared__ unsigned int is_last;

  const int tid  = threadIdx.x;
  const int lane = tid & 63;
  const int w    = tid >> 6;      // wave 0..3
  const int rh   = w >> 1;        // row half: rows rh*64..+64
  const int wc   = w & 1;         // col half: cols wc*512..+512 of strip
  const int strip = blockIdx.x;   // 0..7 -> XCD-pinned (linear%8 == x)
  const int rg   = blockIdx.y;    // 0..63: rows rg*128..+128
  const int quad = lane >> 4;
  const int l15  = lane & 15;

  // ---- stage A once: 16 global_load_lds (proven swizzled staging) ----
  const int srow = tid >> 3;                        // 0..31
  const int sgrp = ((tid & 7) ^ (srow & 7)) * 8;    // swizzled k-offset
#pragma unroll
  for (int kc = 0; kc < 4; ++kc)
#pragma unroll
    for (int sg = 0; sg < 4; ++sg) {
      const unsigned short* gp =
          A + (size_t)(rg * 128 + sg * 32 + srow) * Cdim + kc * 64 + sgrp;
      unsigned short* lp = &sA[(kc * 128 + sg * 32 + w * 8) * 64];
      __builtin_amdgcn_global_load_lds(
          (const __attribute__((address_space(1))) void*)gp,
          (__attribute__((address_space(3))) void*)lp, 16, 0, 0);
    }
  __syncthreads();  // the ONLY barrier in the main path

  float rowexp[16];
#pragma unroll
  for (int i = 0; i < 16; ++i) rowexp[i] = 0.f;

  const float k2 = 14.4269504089f;  // (1/T) * log2(e)

  // B fragment bases: col = col0 + ni*16 + l15, k-offset quad*8 shorts;
  // per-s offset s*32 shorts = 64 B fits the 13-bit global imm.
  const unsigned short* bb0 =
      Bm + (size_t)(strip * 1024 + wc * 512 + l15) * Cdim + quad * 8;

  for (int cc = 0; cc < 8; ++cc) {
    const unsigned short* bb[4];
#pragma unroll
    for (int ni = 0; ni < 4; ++ni)
      bb[ni] = bb0 + (size_t)(cc * 64 + ni * 16) * Cdim;

    f32x4 acc[4][4];
#pragma unroll
    for (int mi = 0; mi < 4; ++mi)
#pragma unroll
      for (int ni = 0; ni < 4; ++ni) acc[mi][ni] = (f32x4){0.f, 0.f, 0.f, 0.f};

#pragma unroll
    for (int s = 0; s < 8; ++s) {
      const int kc = s >> 1;
      const int g = (s & 1) * 4 + quad;
      bf16x8 bfr[4], afr[4];
#pragma unroll
      for (int ni = 0; ni < 4; ++ni)
        bfr[ni] = *reinterpret_cast<const bf16x8*>(bb[ni] + s * 32);
#pragma unroll
      for (int mi = 0; mi < 4; ++mi) {
        const int row = rh * 64 + mi * 16 + l15;
        afr[mi] = *reinterpret_cast<const bf16x8*>(
            &sA[(kc * 128 + row) * 64 + ((g ^ (l15 & 7)) * 8)]);
      }
#pragma unroll
      for (int mi = 0; mi < 4; ++mi)
#pragma unroll
        for (int ni = 0; ni < 4; ++ni)
          acc[mi][ni] = __builtin_amdgcn_mfma_f32_16x16x32_bf16(
              afr[mi], bfr[ni], acc[mi][ni], 0, 0, 0);
    }

    // accumulate exp row-sums: exp(10*t) = exp2(t * 14.427)
#pragma unroll
    for (int mi = 0; mi < 4; ++mi)
#pragma unroll
      for (int ni = 0; ni < 4; ++ni)
#pragma unroll
        for (int r = 0; r < 4; ++r)
          rowexp[mi * 4 + r] += __builtin_amdgcn_exp2f(acc[mi][ni][r] * k2);
  }

  // ---- epilogue: one reduce + atomic per row slot ----
#pragma unroll
  for (int idx = 0; idx < 16; ++idx) {
    float se = rowexp[idx];
    se += __shfl_xor(se, 1);
    se += __shfl_xor(se, 2);
    se += __shfl_xor(se, 4);
    se += __shfl_xor(se, 8);
    if (l15 == 0) {
      const int row = rg * 128 + rh * 64 + (idx >> 2) * 16 + quad * 4 + (idx & 3);
      atomicAdd(&sumexp[row], se);
    }
  }

  // ---- last block finalizes the loss ----
  if (tid == 0) {
    __threadfence();
    is_last = (atomicAdd(done, 1u) == NBLK - 1) ? 1u : 0u;
  }
  __syncthreads();
  if (is_last) {
    __threadfence();  // acquire: all blocks' sumexp atomics visible
    float lsum = 0.f;
    for (int i = tid; i < Nvec; i += 256) lsum += logf(sumexp[i]);
    // analytic positive-sum: P = 10 * sum_b sum_c rgbsum[b][c]*xsum[b][c]
    float pp = 0.f;
#pragma unroll
    for (int b = 0; b < 8; ++b)
      pp += bsums[b * 256 + tid] * bsums[2048 + b * 256 + tid];
#pragma unroll
    for (int off = 1; off < 64; off <<= 1) {
      lsum += __shfl_xor(lsum, off);
      pp   += __shfl_xor(pp, off);
    }
    if ((tid & 63) == 0) { part4[w] = lsum; part4b[w] = pp; }
    __syncthreads();
    if (tid == 0) {
      float total_lse = 0.f, P = 0.f;
#pragma unroll
      for (int i = 0; i < 4; ++i) { total_lse += part4[i]; P += part4b[i]; }
      P *= 10.0f;
      out[0] = -(P - 1024.0f * total_lse) / (8388608.0f + 1e-8f);
    }
  }
}

extern "C" void kernel_launch(void* const* d_in, const int* in_sizes, int n_in,
                              void* d_out, int out_size, void* d_ws,
                              size_t ws_size, hipStream_t stream) {
  const float* rgb = (const float*)d_in[0];
  const float* x   = (const float*)d_in[1];
  char* ws = (char*)d_ws;
  unsigned short* rgbn = (unsigned short*)ws;                            // 4 MiB
  unsigned short* xn   = (unsigned short*)(ws + (size_t)4 * 1024 * 1024);// 4 MiB
  float* sumexp = (float*)(ws + (size_t)8 * 1024 * 1024);  // 8192 floats
  float* bsums  = sumexp + Nvec;                           // 2x8x256 floats
  unsigned int* done = (unsigned int*)(bsums + 4096);

  hipMemsetAsync(sumexp, 0, (Nvec + 4096 + 4) * sizeof(float), stream);
  norm_kernel<<<dim3(256, 2), 256, 0, stream>>>(rgb, x, rgbn, xn, bsums);
  gemm_loss_kernel<<<dim3(8, 64), 256, 0, stream>>>(rgbn, xn, sumexp, bsums,
                                                    done, (float*)d_out);
}

// Round 9
// 117.138 us; speedup vs baseline: 1.3675x; 1.3675x over previous
//
#include <hip/hip_runtime.h>
#include <hip/hip_bf16.h>

// CrossModalContrastiveLoss: B=8, C=256, H=W=32 -> N=8192 vectors of dim 256.
// loss = -( P - 1024 * sum_i log(sum_j exp(S_ij)) ) / 8388608,
// S = normalize(rgb) @ normalize(x)^T / 0.1.
// P analytic via bilinearity: positives for row i are cols j%8 == i/1024 ->
// P = ln2 * sum_b <sum_{i in b} A_q,i , sum_{j%8==b} x_q,j>  where A_q carries
// the k2 = 10*log2(e) scale folded in at quantization (so S_mfma = k2*sim and
// exp(10*sim) = exp2(S_mfma) with zero epilogue multiplies).
//
// Round-9: fp8 e4m3 GEMM (same MFMA rate as bf16) to break the register
// cliff: A-panel 32 rows/wave = 32 regs (was 128 in bf16/64-row), acc 32,
// total ~110 <= 128 -> 4 waves/SIMD, 4 independent 4-wave blocks/CU
// (LDS 32 KB/block). Barrier convoys interleave 4-way per CU.

#define HWsz 1024
#define Cdim 256
#define Nvec 8192
#define CHW  (Cdim * HWsz)
#define NBLK 1024   // 16 strips x 64 rowgroups

typedef __attribute__((ext_vector_type(4))) float f32x4;

// 32 vectors per block (all one batch), C split 8 ways. Quantizes to fp8
// e4m3 (rgb side pre-scaled by k2), stores (N,C) row-major, and accumulates
// per-batch channel sums of the dequantized values (for analytic P).
__global__ __launch_bounds__(256) void norm_kernel(
    const float* __restrict__ rgb, const float* __restrict__ x,
    unsigned char* __restrict__ rgbq, unsigned char* __restrict__ xq,
    float* __restrict__ bsums) {
  __shared__ float ssp[8][32];
  __shared__ __align__(16) unsigned char tile[32][272];  // 272 = 16*17
  const int t = threadIdx.x;
  const int nl = t & 31;        // vector within block
  const int part = t >> 5;      // 0..7: channel chunk
  const int isx = blockIdx.y;
  const float* src = isx ? x : rgb;
  unsigned char* dst = isx ? xq : rgbq;
  const int n0 = blockIdx.x * 32;
  const int n = n0 + nl;
  const int b = n >> 10;        // uniform per block
  const int hw = n & 1023;
  const float* p = src + (size_t)b * CHW + (size_t)(part * 32) * HWsz + hw;

  float v[32];
  float ss = 0.f;
#pragma unroll
  for (int j = 0; j < 32; ++j) {
    v[j] = p[(size_t)j * HWsz];
    ss += v[j] * v[j];
  }
  ssp[part][nl] = ss;
  __syncthreads();
  float tot = 0.f;
#pragma unroll
  for (int q = 0; q < 8; ++q) tot += ssp[q][nl];
  const float k2 = 14.4269504089f;  // (1/T) * log2(e), folded into rgb side
  const float inv = (isx ? 1.0f : k2) / fmaxf(sqrtf(tot), 1e-12f);

#pragma unroll
  for (int c0 = 0; c0 < 32; c0 += 4) {
    int pk = 0;
    pk = __builtin_amdgcn_cvt_pk_fp8_f32(v[c0] * inv, v[c0 + 1] * inv, pk, false);
    pk = __builtin_amdgcn_cvt_pk_fp8_f32(v[c0 + 2] * inv, v[c0 + 3] * inv, pk, true);
    *reinterpret_cast<unsigned int*>(&tile[nl][part * 32 + c0]) =
        (unsigned int)pk;
  }
  __syncthreads();

  // coalesced store: 2 passes x (16 rows x 256 B)
#pragma unroll
  for (int pass = 0; pass < 2; ++pass) {
    const int r = pass * 16 + (t >> 4);
    const int ck = (t & 15) * 16;
    *reinterpret_cast<uint4*>(dst + (size_t)(n0 + r) * Cdim + ck) =
        *reinterpret_cast<const uint4*>(&tile[r][ck]);
  }

  // per-channel column sum of DEQUANTIZED values (exactly what MFMA sees)
  float csum = 0.f;
#pragma unroll
  for (int r = 0; r < 32; ++r)
    csum += __builtin_amdgcn_cvt_f32_fp8((unsigned int)tile[r][t], 0);
  atomicAdd(&bsums[(isx ? 2048 : 0) + b * 256 + t], csum);
}

// Block = 4 waves, 128 rows x 512-col strip, fp8. A-panel 32 rows/wave in
// regs (8 s-steps x 2 mi longs = 32 VGPRs). B streamed as 8 chunks of 64
// cols x 256 K through double-buffered 2x16 KB LDS.
//
// fp8 LDS swizzle (16-B staging granule): col's 16 units placed at
//   phys(unit) = ((unit>>1) ^ (col&7) ^ ((unit&1)<<2)) + ((unit&1)<<3)
// i.e. even units (k-halves read by quads 0/1) land in slots 0..7, odd units
// (quads 2/3) in slots 8..15, each XOR-spread by col&7, with quads 2/3
// offset by 4 so their mod-128 window interleaves quads 0/1's. Residual
// aliasing on ds_read_b64 is 4 lanes/bank (inherent 512 B/instr; ~1.58x on
// the ds pipe only). Inverted on the GLOBAL address side so the wave-uniform
// base + lane*16 constraint of global_load_lds is preserved.
__global__ __launch_bounds__(256, 4) void gemm_loss_kernel(
    const unsigned char* __restrict__ A, const unsigned char* __restrict__ Bq,
    float* __restrict__ sumexp, const float* __restrict__ bsums,
    unsigned int* __restrict__ done, float* __restrict__ out) {
  __shared__ __align__(16) unsigned char sB[2][16384];
  __shared__ float part4[4], part4b[4];
  __shared__ unsigned int is_last;

  const int tid  = threadIdx.x;
  const int lane = tid & 63;
  const int w    = tid >> 6;      // wave 0..3 -> rows w*32..+32
  const int strip = blockIdx.x;   // 0..15: cols strip*512..+512 (XCD-pinned)
  const int rg   = blockIdx.y;    // 0..63: rows rg*128..+128
  const int quad = lane >> 4;
  const int l15  = lane & 15;

  // ---- A fragments: direct global -> 32 regs/wave, once per block ----
  long areg[8][2];
#pragma unroll
  for (int mi = 0; mi < 2; ++mi) {
    const unsigned char* rp =
        A + (size_t)(rg * 128 + w * 32 + mi * 16 + l15) * Cdim + quad * 8;
#pragma unroll
    for (int s = 0; s < 8; ++s)
      areg[s][mi] = *reinterpret_cast<const long*>(rp + s * 32);
  }

  // staging lane constants: lane = c4*16 + u writes (col base+c4, slot u)
  const int u_  = l15;
  const int c4  = quad;
  const int gx  = (u_ & 7) ^ ((u_ >> 3) << 2);
  const int godd = u_ >> 3;   // global unit parity this slot holds
  // reader lane constants
  const int sxor = (l15 & 7) ^ ((quad >> 1) << 2);
  const int boff = ((quad >> 1) << 7) + ((quad & 1) << 3);

  float rowexp[8];
#pragma unroll
  for (int i = 0; i < 8; ++i) rowexp[i] = 0.f;

  const unsigned char* Bbase = Bq + (size_t)strip * 512 * Cdim;

  // prefetch chunk 0
#pragma unroll
  for (int i = 0; i < 4; ++i) {
    const int colw = w * 16 + i * 4 + c4;
    const unsigned char* gp = Bbase + (size_t)colw * Cdim +
                              32 * (gx ^ (colw & 7)) + godd * 16;
    unsigned char* lp = &sB[0][(w * 16 + i * 4) * 256];
    __builtin_amdgcn_global_load_lds(
        (const __attribute__((address_space(1))) void*)gp,
        (__attribute__((address_space(3))) void*)lp, 16, 0, 0);
  }
  __syncthreads();

  for (int c = 0; c < 8; ++c) {
    const int bf = c & 1;
    if (c < 7) {  // prefetch next chunk (overlaps this chunk's MFMA)
#pragma unroll
      for (int i = 0; i < 4; ++i) {
        const int colw = w * 16 + i * 4 + c4;
        const unsigned char* gp = Bbase + (size_t)((c + 1) * 64 + colw) * Cdim +
                                  32 * (gx ^ (colw & 7)) + godd * 16;
        unsigned char* lp = &sB[bf ^ 1][(w * 16 + i * 4) * 256];
        __builtin_amdgcn_global_load_lds(
            (const __attribute__((address_space(1))) void*)gp,
            (__attribute__((address_space(3))) void*)lp, 16, 0, 0);
      }
    }

    f32x4 acc[2][4];
#pragma unroll
    for (int mi = 0; mi < 2; ++mi)
#pragma unroll
      for (int ni = 0; ni < 4; ++ni) acc[mi][ni] = (f32x4){0.f, 0.f, 0.f, 0.f};

#pragma unroll
    for (int s = 0; s < 8; ++s) {
      const int soff = ((s ^ sxor) << 4) + boff;
      long bfr[4];
#pragma unroll
      for (int ni = 0; ni < 4; ++ni)
        bfr[ni] = *reinterpret_cast<const long*>(
            &sB[bf][(ni * 16 + l15) * 256 + soff]);
#pragma unroll
      for (int mi = 0; mi < 2; ++mi)
#pragma unroll
        for (int ni = 0; ni < 4; ++ni)
          acc[mi][ni] = __builtin_amdgcn_mfma_f32_16x16x32_fp8_fp8(
              areg[s][mi], bfr[ni], acc[mi][ni], 0, 0, 0);
    }

    // rowexp += exp2(S_mfma)  (k2 pre-folded into A)
#pragma unroll
    for (int mi = 0; mi < 2; ++mi)
#pragma unroll
      for (int ni = 0; ni < 4; ++ni)
#pragma unroll
        for (int r = 0; r < 4; ++r)
          rowexp[mi * 4 + r] += __builtin_amdgcn_exp2f(acc[mi][ni][r]);

    __syncthreads();  // buffer reuse; prefetch had full compute to land
  }

  // ---- epilogue: one reduce + atomic per row slot ----
#pragma unroll
  for (int idx = 0; idx < 8; ++idx) {
    float se = rowexp[idx];
    se += __shfl_xor(se, 1);
    se += __shfl_xor(se, 2);
    se += __shfl_xor(se, 4);
    se += __shfl_xor(se, 8);
    if (l15 == 0) {
      const int row =
          rg * 128 + w * 32 + (idx >> 2) * 16 + quad * 4 + (idx & 3);
      atomicAdd(&sumexp[row], se);
    }
  }

  // ---- last block finalizes the loss ----
  if (tid == 0) {
    __threadfence();
    is_last = (atomicAdd(done, 1u) == NBLK - 1) ? 1u : 0u;
  }
  __syncthreads();
  if (is_last) {
    __threadfence();  // acquire: all blocks' sumexp atomics visible
    float lsum = 0.f;
    for (int i = tid; i < Nvec; i += 256) lsum += logf(sumexp[i]);
    // analytic positive-sum: P = ln2 * sum_b <rgbsum_b, xsum_b>
    float pp = 0.f;
#pragma unroll
    for (int b = 0; b < 8; ++b)
      pp += bsums[b * 256 + tid] * bsums[2048 + b * 256 + tid];
#pragma unroll
    for (int off = 1; off < 64; off <<= 1) {
      lsum += __shfl_xor(lsum, off);
      pp   += __shfl_xor(pp, off);
    }
    if ((tid & 63) == 0) { part4[w] = lsum; part4b[w] = pp; }
    __syncthreads();
    if (tid == 0) {
      float total_lse = 0.f, P = 0.f;
#pragma unroll
      for (int i = 0; i < 4; ++i) { total_lse += part4[i]; P += part4b[i]; }
      P *= 0.69314718056f;  // ln 2
      out[0] = -(P - 1024.0f * total_lse) / (8388608.0f + 1e-8f);
    }
  }
}

extern "C" void kernel_launch(void* const* d_in, const int* in_sizes, int n_in,
                              void* d_out, int out_size, void* d_ws,
                              size_t ws_size, hipStream_t stream) {
  const float* rgb = (const float*)d_in[0];
  const float* x   = (const float*)d_in[1];
  char* ws = (char*)d_ws;
  unsigned char* rgbq = (unsigned char*)ws;                             // 2 MiB
  unsigned char* xq   = (unsigned char*)(ws + (size_t)2 * 1024 * 1024); // 2 MiB
  float* sumexp = (float*)(ws + (size_t)4 * 1024 * 1024);  // 8192 floats
  float* bsums  = sumexp + Nvec;                           // 2x8x256 floats
  unsigned int* done = (unsigned int*)(bsums + 4096);

  hipMemsetAsync(sumexp, 0, (Nvec + 4096 + 4) * sizeof(float), stream);
  norm_kernel<<<dim3(256, 2), 256, 0, stream>>>(rgb, x, rgbq, xq, bsums);
  gemm_loss_kernel<<<dim3(16, 64), 256, 0, stream>>>(rgbq, xq, sumexp, bsums,
                                                     done, (float*)d_out);
}